// Round 3
// baseline (439.642 us; speedup 1.0000x reference)
//
#include <hip/hip_runtime.h>

// x [N=8, C=64, D=16, H=128, W=128] f32, bias [64] f32.
// out = tanh(softmax_C(mean_D(x) + bias)) * 2, f32 [N,C,H,W].
constexpr int C  = 64;
constexpr int D  = 16;
constexpr int HW = 128 * 128;
constexpr float SCALING = 2.0f;

// Fused single pass: one thread per (n,h,w) column; 64 logits in registers.
// __launch_bounds__(256, 2): min 2 waves/SIMD -> 256-VGPR budget, so the
// 64-entry logit array stays in VGPRs (round-0 default budget spilled it
// at 52 VGPRs -> 4x slowdown). Channel-outer / depth-inner keeps only ~16
// load results + partial sums live inside each channel's reduction.
__global__ __launch_bounds__(256, 2) void fused_mean_softmax_tanh(
    const float* __restrict__ x,
    const float* __restrict__ bias,
    float* __restrict__ out)
{
    const int idx = blockIdx.x * 256 + threadIdx.x;   // 0 .. N*HW-1
    const int n = idx >> 14;                          // HW = 2^14
    const int s = idx & (HW - 1);

    const float* px = x + (size_t)n * C * D * HW + s;

    float logit[C];

    #pragma unroll
    for (int c = 0; c < C; ++c) {
        const float* p = px + (size_t)c * D * HW;
        float a0 = 0.f, a1 = 0.f, a2 = 0.f, a3 = 0.f;
        #pragma unroll
        for (int d = 0; d < D; d += 4) {
            a0 += p[(size_t)(d + 0) * HW];
            a1 += p[(size_t)(d + 1) * HW];
            a2 += p[(size_t)(d + 2) * HW];
            a3 += p[(size_t)(d + 3) * HW];
        }
        logit[c] = ((a0 + a1) + (a2 + a3)) * (1.0f / D) + bias[c];
    }

    float mx = logit[0];
    #pragma unroll
    for (int c = 1; c < C; ++c) mx = fmaxf(mx, logit[c]);

    float sum = 0.f;
    #pragma unroll
    for (int c = 0; c < C; ++c) {
        logit[c] = __expf(logit[c] - mx);
        sum += logit[c];
    }
    const float inv = 1.0f / sum;

    float* po = out + (size_t)n * C * HW + s;
    #pragma unroll
    for (int c = 0; c < C; ++c) {
        const float p = logit[c] * inv;            // in (0, 1]
        const float e = __expf(2.0f * p);          // tanh(p) = 1 - 2/(e^{2p}+1)
        po[(size_t)c * HW] = SCALING * (1.0f - 2.0f / (e + 1.0f));
    }
}

extern "C" void kernel_launch(void* const* d_in, const int* in_sizes, int n_in,
                              void* d_out, int out_size, void* d_ws, size_t ws_size,
                              hipStream_t stream)
{
    const float* x    = (const float*)d_in[0];
    const float* bias = (const float*)d_in[1];
    float* out        = (float*)d_out;

    const int N     = in_sizes[0] / (C * D * HW);   // = 8
    const int total = N * HW;                       // 131072 threads
    fused_mean_softmax_tanh<<<total / 256, 256, 0, stream>>>(x, bias, out);
}

// Round 4
// 116.739 us; speedup vs baseline: 3.7660x; 3.7660x over previous
//
#include <hip/hip_runtime.h>

// x [N=8, C=64, D=16, H=128, W=128] f32, bias [64] f32.
// out = tanh(softmax_C(mean_D(x) + bias)) * 2, f32 [N,C,H,W].
//
// Fused via LDS (round 0/3 lesson: one-thread-per-column needs 64 live
// logit regs; the backend refuses >52 VGPRs and spills to L2-resident
// scratch -> 4x slowdown. So keep per-thread state <= 16 accumulators and
// cooperate through LDS instead).
constexpr int C     = 64;
constexpr int D     = 16;
constexpr int HW    = 128 * 128;
constexpr int STILE = 128;               // spatial positions per block
constexpr float SCALING = 2.0f;

__global__ __launch_bounds__(256) void fused_lds(
    const float* __restrict__ x,
    const float* __restrict__ bias,
    float* __restrict__ out)
{
    __shared__ float logit[C][STILE];    // 32 KB
    __shared__ float red[2][2][STILE];   // [max|sum][half][s], 2 KB

    const int b      = blockIdx.x;
    const int n      = b >> 7;           // HW/STILE = 128 tiles per image
    const int s_base = (b & 127) * STILE;

    // ---------- Phase 1: mean over depth, 16 channels per thread ----------
    // thread = (group g: 16 channels) x (q: one float2 slot of the s-tile).
    // Wave lanes q=0..63 -> 64 consecutive float2 = 512B per (c,d): coalesced.
    const int q = threadIdx.x & 63;
    const int g = threadIdx.x >> 6;

    #pragma unroll
    for (int k = 0; k < 16; ++k) {
        const int c = g * 16 + k;
        const float2* p =
            (const float2*)(x + ((size_t)(n * C + c) * D) * HW + s_base) + q;
        float2 a0 = {0.f, 0.f}, a1 = {0.f, 0.f};
        #pragma unroll
        for (int d = 0; d < D; d += 2) {
            float2 v0 = p[(size_t)(d + 0) * (HW / 2)];
            float2 v1 = p[(size_t)(d + 1) * (HW / 2)];
            a0.x += v0.x; a0.y += v0.y;
            a1.x += v1.x; a1.y += v1.y;
        }
        float2 r;
        r.x = (a0.x + a1.x) * (1.0f / D) + bias[c];
        r.y = (a0.y + a1.y) * (1.0f / D) + bias[c];
        *(float2*)&logit[c][2 * q] = r;
    }
    __syncthreads();

    // ---------- Phase 2: softmax over C + tanh, cooperative ----------
    // thread owns s-column `s`, channel half h (32 channels).
    const int s  = threadIdx.x & 127;
    const int h  = threadIdx.x >> 7;
    const int c0 = h * 32;

    float pmax = -INFINITY;
    #pragma unroll
    for (int c = 0; c < 32; ++c) pmax = fmaxf(pmax, logit[c0 + c][s]);
    red[0][h][s] = pmax;
    __syncthreads();
    const float m = fmaxf(red[0][0][s], red[0][1][s]);

    float psum = 0.f;
    #pragma unroll
    for (int c = 0; c < 32; ++c) {
        const float v = __expf(logit[c0 + c][s] - m);
        logit[c0 + c][s] = v;              // in-place; slot owned by this thread
        psum += v;
    }
    red[1][h][s] = psum;
    __syncthreads();
    const float inv = 1.0f / (red[1][0][s] + red[1][1][s]);

    float* po = out + (size_t)(n * C + c0) * HW + s_base + s;
    #pragma unroll
    for (int c = 0; c < 32; ++c) {
        const float pv = logit[c0 + c][s] * inv;      // in (0, 1]
        const float e  = __expf(2.0f * pv);           // tanh via exp
        po[(size_t)c * HW] = SCALING * (1.0f - 2.0f / (e + 1.0f));
    }
}

extern "C" void kernel_launch(void* const* d_in, const int* in_sizes, int n_in,
                              void* d_out, int out_size, void* d_ws, size_t ws_size,
                              hipStream_t stream)
{
    const float* x    = (const float*)d_in[0];
    const float* bias = (const float*)d_in[1];
    float* out        = (float*)d_out;

    const int N      = in_sizes[0] / (C * D * HW);   // = 8
    const int blocks = N * (HW / STILE);             // 1024
    fused_lds<<<blocks, 256, 0, stream>>>(x, bias, out);
}

// Round 5
// 112.284 us; speedup vs baseline: 3.9154x; 1.0397x over previous
//
#include <hip/hip_runtime.h>

// x [N=8, C=64, D=16, H=128, W=128] f32, bias [64] f32.
// out = tanh(softmax_C(mean_D(x) + bias)) * 2, f32 [N,C,H,W].
//
// Round-3 lesson: per-thread-64-logit layout spills (allocator pins 52 VGPR).
// Round-4: LDS-cooperative fused = 116.7us (~75% of ceiling) with float2 loads.
// This round: float4 loads (16B/lane sweet spot), STILE=256, 512 threads,
// 68KB LDS -> 2 blocks/CU, launch_bounds(512,4) -> 128-VGPR budget (matches
// LDS-capped occupancy; no spill, deep load pipelines).
constexpr int C     = 64;
constexpr int D     = 16;
constexpr int HW    = 128 * 128;
constexpr int HW4   = HW / 4;
constexpr int STILE = 256;               // spatial positions per block
constexpr float SCALING = 2.0f;

__global__ __launch_bounds__(512, 4) void fused_lds_v2(
    const float* __restrict__ x,
    const float* __restrict__ bias,
    float* __restrict__ out)
{
    __shared__ float logit[C][STILE];    // 64 KB
    __shared__ float red[2][2][STILE];   // [max|sum][half][s], 4 KB

    const int b      = blockIdx.x;
    const int n      = b >> 6;           // HW/STILE = 64 tiles per image
    const int s_base = (b & 63) * STILE;

    // ---------- Phase 1: mean over depth, float4 streams ----------
    // thread = (group g of 8 channels) x (q: one float4 slot of the s-tile).
    // Wave lanes q=0..63 -> 64 consecutive float4 = 1KB per (c,d): ideal.
    const int q = threadIdx.x & 63;
    const int g = threadIdx.x >> 6;      // 0..7

    #pragma unroll
    for (int k = 0; k < 8; ++k) {
        const int c = g * 8 + k;
        const float4* p =
            (const float4*)(x + ((size_t)(n * C + c) * D) * HW + s_base) + q;
        float4 a0 = {0,0,0,0}, a1 = a0, a2 = a0, a3 = a0;
        #pragma unroll
        for (int d = 0; d < D; d += 4) {
            float4 v0 = p[(size_t)(d + 0) * HW4];
            float4 v1 = p[(size_t)(d + 1) * HW4];
            float4 v2 = p[(size_t)(d + 2) * HW4];
            float4 v3 = p[(size_t)(d + 3) * HW4];
            a0.x += v0.x; a0.y += v0.y; a0.z += v0.z; a0.w += v0.w;
            a1.x += v1.x; a1.y += v1.y; a1.z += v1.z; a1.w += v1.w;
            a2.x += v2.x; a2.y += v2.y; a2.z += v2.z; a2.w += v2.w;
            a3.x += v3.x; a3.y += v3.y; a3.z += v3.z; a3.w += v3.w;
        }
        const float bc = bias[c];
        float4 r;
        r.x = ((a0.x + a1.x) + (a2.x + a3.x)) * (1.0f / D) + bc;
        r.y = ((a0.y + a1.y) + (a2.y + a3.y)) * (1.0f / D) + bc;
        r.z = ((a0.z + a1.z) + (a2.z + a3.z)) * (1.0f / D) + bc;
        r.w = ((a0.w + a1.w) + (a2.w + a3.w)) * (1.0f / D) + bc;
        *(float4*)&logit[c][4 * q] = r;
    }
    __syncthreads();

    // ---------- Phase 2: softmax over C + tanh, cooperative ----------
    // thread owns s-column `s`, channel half h (32 channels).
    const int s  = threadIdx.x & 255;
    const int h  = threadIdx.x >> 8;     // 0..1
    const int c0 = h * 32;

    float pmax = -INFINITY;
    #pragma unroll
    for (int c = 0; c < 32; ++c) pmax = fmaxf(pmax, logit[c0 + c][s]);
    red[0][h][s] = pmax;
    __syncthreads();
    const float m = fmaxf(red[0][0][s], red[0][1][s]);

    float psum = 0.f;
    #pragma unroll
    for (int c = 0; c < 32; ++c) {
        const float v = __expf(logit[c0 + c][s] - m);
        logit[c0 + c][s] = v;            // slot owned by this thread
        psum += v;
    }
    red[1][h][s] = psum;
    __syncthreads();
    const float inv = 1.0f / (red[1][0][s] + red[1][1][s]);

    float* po = out + (size_t)(n * C + c0) * HW + s_base + s;
    #pragma unroll
    for (int c = 0; c < 32; ++c) {
        const float pv = logit[c0 + c][s] * inv;      // in (0, 1]
        const float e  = __expf(2.0f * pv);           // tanh via exp
        po[(size_t)c * HW] = SCALING * (1.0f - 2.0f / (e + 1.0f));
    }
}

extern "C" void kernel_launch(void* const* d_in, const int* in_sizes, int n_in,
                              void* d_out, int out_size, void* d_ws, size_t ws_size,
                              hipStream_t stream)
{
    const float* x    = (const float*)d_in[0];
    const float* bias = (const float*)d_in[1];
    float* out        = (float*)d_out;

    const int N      = in_sizes[0] / (C * D * HW);   // = 8
    const int blocks = N * (HW / STILE);             // 512
    fused_lds_v2<<<blocks, 512, 0, stream>>>(x, bias, out);
}